// Round 6
// baseline (36.691 us; speedup 1.0000x reference)
//
#include <hip/hip_runtime.h>
#include <cstdint>
#include <math.h>

#define N_FRAMES 16777216            // 2^24
#define MAX_BEATS (N_FRAMES / 8)     // 2097152
#define NTHREADS 256
#define WTILE 2048                   // elems per wave-tile
#define NTILE (N_FRAMES / WTILE)     // 8192
#define NBLK (NTILE / 4)             // 2048 blocks (4 waves each)

typedef unsigned int u32;
typedef unsigned long long u64;

__device__ __forceinline__ float max3f(float a, float b, float c) {
  return fmaxf(fmaxf(a, b), c);
}

// deposit 8 bits into every 4th bit position of a u32
__device__ __forceinline__ u32 spread4(u32 x) {
  x = (x | (x << 12)) & 0x000F000Fu;
  x = (x | (x << 6))  & 0x03030303u;
  x = (x | (x << 3))  & 0x11111111u;
  return x;
}

// peak lookup in ballot-layout mask array: elem e -> tile e>>11, group (e>>8)&7,
// ballot b = e&3, bit i = (e>>2)&63
__device__ __forceinline__ int peak_from_masks(const u64* __restrict__ masks, int e) {
  const int q = e >> 11, k = (e >> 8) & 7, b = e & 3, i = (e >> 2) & 63;
  return (int)((masks[(size_t)q * 32 + k * 4 + b] >> i) & 1ull);
}

// k_count: fully-coalesced interleaved loads; halos via shfl; ballot masks; scalar counts.
__global__ __launch_bounds__(NTHREADS) void k_count(const float* __restrict__ x,
                                                    int* __restrict__ counts,
                                                    u64* __restrict__ masks) {
  const int t = threadIdx.x, lane = t & 63, wv = t >> 6;
  const int q = blockIdx.x * 4 + wv;
  const int base = q * WTILE;

  // group k: lane owns elements base + 256k + 4*lane .. +3  (load = 1KB contiguous/wave)
  float4 g[8];
  const float4* px = reinterpret_cast<const float4*>(x + base);
#pragma unroll
  for (int k = 0; k < 8; ++k) g[k] = px[k * 64 + lane];

  // tile-edge halos (only lanes 0/63 consume)
  float4 eL = make_float4(-INFINITY, -INFINITY, -INFINITY, -INFINITY);
  float4 eR = eL;
  if (lane == 0 && base >= 4) eL = *reinterpret_cast<const float4*>(x + base - 4);
  if (lane == 63 && base + WTILE + 4 <= N_FRAMES)
    eR = *reinterpret_cast<const float4*>(x + base + WTILE);

  // peak at base-1 (uniform via ballot); lane 0 has eL=-INFs when base==0 -> false
  bool pkm1 = false;
  if (lane == 0) {
    const float c = eL.w;  // element base-1
    const float m = max3f(max3f(eL.x, eL.y, eL.z), g[0].x, fmaxf(g[0].y, g[0].z));
    pkm1 = (c > 0.0f) && (c >= m);
  }
  u64 carry = __ballot(pkm1) & 1ull;

  int cnt = 0;
#pragma unroll
  for (int k = 0; k < 8; ++k) {
    const float4 f = g[k];
    // halo: left = lane-1's (y,z,w), right = lane+1's (x,y,z)
    float l1 = __shfl_up(f.y, 1, 64), l2 = __shfl_up(f.z, 1, 64), l3 = __shfl_up(f.w, 1, 64);
    float r1 = __shfl_down(f.x, 1, 64), r2 = __shfl_down(f.y, 1, 64), r3 = __shfl_down(f.z, 1, 64);
    float a1, a2, a3, b1, b2, b3;
    if (k > 0) { a1 = __shfl(g[k - 1].y, 63, 64); a2 = __shfl(g[k - 1].z, 63, 64); a3 = __shfl(g[k - 1].w, 63, 64); }
    else       { a1 = eL.y; a2 = eL.z; a3 = eL.w; }
    if (k < 7) { b1 = __shfl(g[k + 1].x, 0, 64); b2 = __shfl(g[k + 1].y, 0, 64); b3 = __shfl(g[k + 1].z, 0, 64); }
    else       { b1 = eR.x; b2 = eR.y; b3 = eR.z; }
    if (lane == 0)  { l1 = a1; l2 = a2; l3 = a3; }
    if (lane == 63) { r1 = b1; r2 = b2; r3 = b3; }

    // s = [l1,l2,l3, c0,c1,c2,c3, r1,r2,r3]; trio maxes
    const float T0 = max3f(l1, l2, l3);
    const float T1 = max3f(l2, l3, f.x);
    const float T2 = max3f(l3, f.x, f.y);
    const float T3 = max3f(f.x, f.y, f.z);
    const float T4 = max3f(f.y, f.z, f.w);
    const float T5 = max3f(f.z, f.w, r1);
    const float T6 = max3f(f.w, r1, r2);
    const float T7 = max3f(r1, r2, r3);
    const bool p0 = (f.x > 0.0f) && (f.x >= fmaxf(T0, T4));
    const bool p1 = (f.y > 0.0f) && (f.y >= fmaxf(T1, T5));
    const bool p2 = (f.z > 0.0f) && (f.z >= fmaxf(T2, T6));
    const bool p3 = (f.w > 0.0f) && (f.w >= fmaxf(T3, T7));
    const u64 B0 = __ballot(p0), B1 = __ballot(p1), B2 = __ballot(p2), B3 = __ballot(p3);

    // run starts (element order: prev of (b=0,i) is (b=3,i-1); prev of (b,i) is (b-1,i))
    const u64 S0 = B0 & ~((B3 << 1) | carry);
    const u64 S1 = B1 & ~B0;
    const u64 S2 = B2 & ~B1;
    const u64 S3 = B3 & ~B2;
    cnt += __popcll(S0) + __popcll(S1) + __popcll(S2) + __popcll(S3);
    carry = B3 >> 63;

    if (lane < 4) {
      const u64 val = (lane == 0) ? B0 : (lane == 1) ? B1 : (lane == 2) ? B2 : B3;
      masks[(size_t)q * 32 + k * 4 + lane] = val;
    }
  }
  if (lane == 0) counts[q] = cnt;
}

// k_emit: inlined global scan over counts[NTILE]; per-lane contiguous mask rebuilt
// from ballots via spread4; emits section averages + -1 tail.
__global__ __launch_bounds__(NTHREADS) void k_emit(const u64* __restrict__ masks,
                                                   const int* __restrict__ counts,
                                                   float* __restrict__ out) {
  __shared__ int s_wtot[4];
  __shared__ int s_texcl[NTHREADS];
  __shared__ int s_off[4];
  __shared__ int s_total;
  const int t = threadIdx.x, lane = t & 63, wv = t >> 6;

  // global scan recompute: thread t owns counts[32t .. 32t+32)
  int s = 0;
  const int cb = t * 32;
#pragma unroll
  for (int e = 0; e < 32; ++e) s += counts[cb + e];
  int incl = s;
#pragma unroll
  for (int off = 1; off < 64; off <<= 1) {
    const int vv = __shfl_up(incl, off, 64);
    if (lane >= off) incl += vv;
  }
  s_texcl[t] = incl - s;
  if (lane == 63) s_wtot[wv] = incl;
  __syncthreads();
  if (t == 0) s_total = s_wtot[0] + s_wtot[1] + s_wtot[2] + s_wtot[3];
  if (t < 4) {
    const int target = blockIdx.x * 4 + t;     // tile id
    const int j = target >> 5, r = target & 31;
    int wb = 0;
    for (int ww = 0; ww < (j >> 6); ++ww) wb += s_wtot[ww];
    int pfx = wb + s_texcl[j];
    for (int e = 0; e < r; ++e) pfx += counts[j * 32 + e];
    s_off[t] = pfx;
  }
  __syncthreads();

  const int q = blockIdx.x * 4 + wv;
  // lane owns elements [q*2048 + 32*lane, +32): group k = lane>>3, bits 8*(lane&7)..+7
  const int k = lane >> 3, sh = (lane & 7) * 8;
  const u64* mb = masks + (size_t)q * 32 + k * 4;
  const u32 c0 = (u32)(mb[0] >> sh) & 0xFFu;
  const u32 c1 = (u32)(mb[1] >> sh) & 0xFFu;
  const u32 c2 = (u32)(mb[2] >> sh) & 0xFFu;
  const u32 c3 = (u32)(mb[3] >> sh) & 0xFFu;
  const u32 m = spread4(c0) | (spread4(c1) << 1) | (spread4(c2) << 2) | (spread4(c3) << 3);

  u32 prevbit = __shfl_up(m, 1, 64) >> 31;
  if (lane == 0) prevbit = (q == 0) ? 0u : (u32)(masks[(size_t)q * 32 - 1] >> 63);
  u32 sm = m & ~((m << 1) | prevbit);
  const int cnt = __popc(sm);

  int incl2 = cnt;
#pragma unroll
  for (int off = 1; off < 64; off <<= 1) {
    const int vv = __shfl_up(incl2, off, 64);
    if (lane >= off) incl2 += vv;
  }
  int sid = s_off[wv] + incl2 - cnt;

  const int gbase = q * WTILE + lane * 32;
  while (sm) {
    const int sb = __builtin_ctz(sm);
    sm &= sm - 1;
    const int i0 = gbase + sb;
    const u32 above = m >> sb;             // bit 0 = this peak
    const int len = (~above == 0u) ? (32 - sb) : __builtin_ctz(~above);
    int end = i0 + len - 1;
    if (sb + len == 32) {                  // run continues past this lane's window (ties; rare)
      int e = gbase + 32;
      while (e < N_FRAMES && peak_from_masks(masks, e)) { end = e; ++e; }
    }
    if (sid < MAX_BEATS)
      out[sid] = (float)(((double)i0 + (double)end) * 0.5);
    ++sid;
  }

  // -1 tail fill: this block covers out[blockIdx*1024 .. +1024)
  const int lo = blockIdx.x * (MAX_BEATS / NBLK);
  const int hi = lo + (MAX_BEATS / NBLK);
  for (int i = max(lo, s_total) + t; i < hi; i += NTHREADS)
    out[i] = -1.0f;
}

extern "C" void kernel_launch(void* const* d_in, const int* in_sizes, int n_in,
                              void* d_out, int out_size, void* d_ws, size_t ws_size,
                              hipStream_t stream) {
  const float* x = (const float*)d_in[0];
  float* out = (float*)d_out;

  u64* masks = (u64*)d_ws;                       // NTILE*32 u64 = 2 MiB
  int* counts = (int*)(masks + (size_t)NTILE * 32);  // NTILE ints = 32 KiB

  k_count<<<NBLK, NTHREADS, 0, stream>>>(x, counts, masks);
  k_emit<<<NBLK, NTHREADS, 0, stream>>>(masks, counts, out);
}

// Round 7
// 28.427 us; speedup vs baseline: 1.2907x; 1.2907x over previous
//
#include <hip/hip_runtime.h>
#include <cstdint>
#include <math.h>

#define N_FRAMES 16777216          // 2^24
#define MAX_BEATS (N_FRAMES / 8)   // 2097152
#define CHUNK 4096
#define NTHREADS 256
#define NCHUNK (N_FRAMES / CHUNK)  // 4096
#define NBLK (NCHUNK / 4)          // 1024 emit blocks (4 waves, 1 chunk each)
#define TOTAL_MASKS ((size_t)NCHUNK * 64)

typedef unsigned long long u64;
typedef unsigned int u32;

__device__ __forceinline__ float max3f(float a, float b, float c) {
  return fmaxf(fmaxf(a, b), c);
}

// k_count: register-window stencil (16 elems/thread, 64B lane stride), trio-max
// sharing, u64 masks + per-chunk counts. No LDS staging of x.
__global__ __launch_bounds__(NTHREADS) void k_count(const float* __restrict__ x,
                                                    int* __restrict__ counts,
                                                    u64* __restrict__ masks) {
  __shared__ u32 m16[NTHREADS];
  __shared__ u32 s_pm1;           // peak at g0-1
  const int b = blockIdx.x;
  const int g0 = b * CHUNK;
  const int t = threadIdx.x;
  const int gbase = g0 + t * 16;

  // v[k] = x[gbase - 4 + k], k in [0,24)
  float v[24];
  if (gbase - 4 >= 0 && gbase + 20 <= N_FRAMES) {
    const float4* p = reinterpret_cast<const float4*>(x + gbase - 4);
#pragma unroll
    for (int k = 0; k < 6; ++k) {
      const float4 f = p[k];
      v[4 * k + 0] = f.x; v[4 * k + 1] = f.y; v[4 * k + 2] = f.z; v[4 * k + 3] = f.w;
    }
  } else {
#pragma unroll
    for (int k = 0; k < 24; ++k) {
      const int gi = gbase - 4 + k;
      v[k] = (gi >= 0 && gi < N_FRAMES) ? x[gi] : -INFINITY;
    }
  }

  // trio maxes: Lt[i] = max(v[i..i+2]); window(e) = max(Lt[e+1], Lt[e+5])
  float Lt[21];
#pragma unroll
  for (int i = 0; i < 21; ++i) Lt[i] = max3f(v[i], v[i + 1], v[i + 2]);

  u32 pm = 0;
#pragma unroll
  for (int e = 0; e < 16; ++e) {
    const float c = v[e + 4];
    const float m = fmaxf(Lt[e + 1], Lt[e + 5]);
    if (c > 0.0f && c >= m) pm |= (1u << e);
  }
  m16[t] = pm;
  if (t == 0) {  // peak at g0-1: center v[3], window trios Lt[0], Lt[4]
    const float c = v[3];
    const float m = fmaxf(Lt[0], Lt[4]);
    s_pm1 = (c > 0.0f && c >= m) ? 1u : 0u;
  }
  __syncthreads();

  if (t < 64) {
    const u64 m = (u64)m16[4 * t] | ((u64)m16[4 * t + 1] << 16) |
                  ((u64)m16[4 * t + 2] << 32) | ((u64)m16[4 * t + 3] << 48);
    masks[((size_t)b << 6) + t] = m;
    const u64 carry = (t == 0) ? (u64)s_pm1 : (u64)((m16[4 * t - 1] >> 15) & 1u);
    int cnt = __popcll(m & ~((m << 1) | carry));
#pragma unroll
    for (int off = 32; off; off >>= 1) cnt += __shfl_down(cnt, off, 64);
    if (t == 0) counts[b] = cnt;
  }
}

// k_emit: 4 waves/block, wave w owns chunk blockIdx.x*4+w. Inlines the global
// scan over counts[NCHUNK] (16 KB, L2-hot). Emits section averages + -1 tail.
__global__ __launch_bounds__(NTHREADS) void k_emit(const u64* __restrict__ masks,
                                                   const int* __restrict__ counts,
                                                   float* __restrict__ out) {
  __shared__ int s_wtot[4];
  __shared__ int s_texcl[NTHREADS];
  __shared__ int s_off[4];
  __shared__ int s_total;
  const int t = threadIdx.x, lane = t & 63, wv = t >> 6;

  // global scan recompute: thread t owns counts[16t .. 16t+16)
  int s = 0;
  const int cb = t * 16;
#pragma unroll
  for (int e = 0; e < 16; ++e) s += counts[cb + e];
  int incl = s;
#pragma unroll
  for (int off = 1; off < 64; off <<= 1) {
    const int vv = __shfl_up(incl, off, 64);
    if (lane >= off) incl += vv;
  }
  s_texcl[t] = incl - s;
  if (lane == 63) s_wtot[wv] = incl;
  __syncthreads();
  if (t == 0) s_total = s_wtot[0] + s_wtot[1] + s_wtot[2] + s_wtot[3];
  if (t < 4) {   // offset of chunk blockIdx.x*4 + t
    const int target = blockIdx.x * 4 + t;
    const int j = target >> 4, r = target & 15;
    int wb = 0;
    for (int ww = 0; ww < (j >> 6); ++ww) wb += s_wtot[ww];
    int pfx = wb + s_texcl[j];
    for (int e = 0; e < r; ++e) pfx += counts[j * 16 + e];
    s_off[t] = pfx;
  }
  __syncthreads();

  const int b = blockIdx.x * 4 + wv;
  const size_t mi = ((size_t)b << 6) + lane;
  const u64 m = masks[mi];
  const u32 myb63 = (u32)(m >> 63);
  u32 prevb = __shfl_up(myb63, 1, 64);
  if (lane == 0) prevb = (b == 0) ? 0u : (u32)(masks[mi - 1] >> 63);
  u64 sm = m & ~((m << 1) | (u64)prevb);
  const int cnt = __popcll(sm);

  int incl2 = cnt;
#pragma unroll
  for (int off = 1; off < 64; off <<= 1) {
    const int vv = __shfl_up(incl2, off, 64);
    if (lane >= off) incl2 += vv;
  }
  int sid = s_off[wv] + incl2 - cnt;

  if (s_off[wv] < MAX_BEATS) {   // chunks entirely past the cutoff emit nothing
    const int gbase = b * CHUNK + lane * 64;
    while (sm) {
      const int sb = __builtin_ctzll(sm);
      sm &= sm - 1;
      const int i0 = gbase + sb;
      const u64 above = m >> sb;           // bit 0 = this peak
      const int len = (~above == 0ull) ? (64 - sb) : __builtin_ctzll(~above);
      int end = i0 + len - 1;
      if (sb + len == 64) {                // run continues into next mask (ties; rare)
        size_t idx = mi + 1;
        while (idx < TOTAL_MASKS) {
          const u64 mm = masks[idx];
          if (~mm == 0ull) { end += 64; ++idx; }
          else { end += __builtin_ctzll(~mm); break; }
        }
      }
      if (sid < MAX_BEATS)
        out[sid] = (float)(((double)i0 + (double)end) * 0.5);
      ++sid;
    }
  }

  // -1 tail fill: this block covers out[blockIdx*2048 .. +2048)
  const int lo = blockIdx.x * (MAX_BEATS / NBLK);
  const int hi = lo + (MAX_BEATS / NBLK);
  for (int i = max(lo, s_total) + t; i < hi; i += NTHREADS)
    out[i] = -1.0f;
}

extern "C" void kernel_launch(void* const* d_in, const int* in_sizes, int n_in,
                              void* d_out, int out_size, void* d_ws, size_t ws_size,
                              hipStream_t stream) {
  const float* x = (const float*)d_in[0];
  float* out = (float*)d_out;

  u64* masks = (u64*)d_ws;                      // 2 MiB
  int* counts = (int*)(masks + TOTAL_MASKS);    // 16 KiB

  k_count<<<NCHUNK, NTHREADS, 0, stream>>>(x, counts, masks);
  k_emit<<<NBLK, NTHREADS, 0, stream>>>(masks, counts, out);
}